// Round 5
// baseline (445.627 us; speedup 1.0000x reference)
//
#include <hip/hip_runtime.h>
#include <math.h>

#define D 128
#define K 1024

typedef __attribute__((ext_vector_type(8))) short bf16x8;
typedef __attribute__((ext_vector_type(4))) float f32x4;
typedef unsigned short u16;

// ws layout:
// [0,4096)        hist (1024 int)
// [4096,4100)     loss accumulator
// [8192,12288)    cnorm (1024 f32)
// [16384,540672)  frag image (512 KB)   -- new: code-major [1024][hi128|lo128] u16
// [540672,1589248) top-2 partials: [32768 rows][2 cg] float4 (v1,v2,i1,i2)

__device__ __forceinline__ u16 f2bf(float x) {
    union { float f; unsigned u; } v; v.f = x;
    unsigned r = (v.u + 0x7FFFu + ((v.u >> 16) & 1u)) >> 16;
    return (u16)r;
}
__device__ __forceinline__ float bf2f(u16 b) {
    union { float f; unsigned u; } v; v.u = ((unsigned)b) << 16;
    return v.f;
}
__device__ __forceinline__ void gll16(const void* g, void* l) {
    __builtin_amdgcn_global_load_lds(
        (const __attribute__((address_space(1))) void*)g,
        (__attribute__((address_space(3))) void*)l, 16, 0, 0);
}

// merge candidate top-2 pair (bv1,bi1,bv2,bi2) into (v1,i1,v2,i2); lower-index tiebreak
__device__ __forceinline__ void t2merge(float& v1, int& i1, float& v2, int& i2,
                                        float bv1, int bi1, float bv2, int bi2) {
    if (bv1 < v1 || (bv1 == v1 && bi1 < i1)) {
        v2 = v1; i2 = i1;
        v1 = bv1; i1 = bi1;
        if (bv2 < v2 || (bv2 == v2 && bi2 < i2)) { v2 = bv2; i2 = bi2; }
    } else {
        if (bv1 < v2 || (bv1 == v2 && bi1 < i2)) { v2 = bv1; i2 = bi1; }
    }
}

// ---------------- NEW PATH ----------------

// codebook -> code-major bf16 hi/lo fragment image + cnorm
__global__ void prep2(const float* __restrict__ cb, u16* __restrict__ frag,
                      float* __restrict__ cnorm) {
    int tid = blockIdx.x * blockDim.x + threadIdx.x;   // 32768: one float4/thread
    int code = tid >> 5, d4 = tid & 31;
    float4 v = reinterpret_cast<const float4*>(cb)[tid];
    u16 h0 = f2bf(v.x), h1 = f2bf(v.y), h2 = f2bf(v.z), h3 = f2bf(v.w);
    u16 l0 = f2bf(v.x - bf2f(h0)), l1 = f2bf(v.y - bf2f(h1));
    u16 l2 = f2bf(v.z - bf2f(h2)), l3 = f2bf(v.w - bf2f(h3));
    u16* base = frag + (size_t)code * 256;
    *reinterpret_cast<ushort4*>(base + d4 * 4) = make_ushort4(h0, h1, h2, h3);
    *reinterpret_cast<ushort4*>(base + 128 + d4 * 4) = make_ushort4(l0, l1, l2, l3);
    float s = v.x * v.x + v.y * v.y + v.z * v.z + v.w * v.w;
#pragma unroll
    for (int m = 1; m <= 16; m <<= 1) s += __shfl_xor(s, m);
    if (d4 == 0) cnorm[code] = s;
}

// block = 512 thr (8 waves). Block (rg, cg) computes rows rg*64..+63 x codes cg*512..+511.
// Codebook fragments live in REGISTERS (64 codes/wave); z tile in LDS. No loop barriers.
__global__ __launch_bounds__(512, 8)
void vq_dist(const float* __restrict__ z, const u16* __restrict__ frag,
             const float* __restrict__ cnorm, float4* __restrict__ part,
             float* __restrict__ out_dist) {
    __shared__ u16 zsh[16384];      // 32 KB z tile (hi 16K | lo 16K), swizzled
    __shared__ float cn_s[512];
    __shared__ float xn_s[64];

    const int t = threadIdx.x;
    const int lane = t & 63;
    const int wave = t >> 6;        // 0..7
    const int lr = lane & 15, lg = lane >> 4;
    const int rg = blockIdx.x >> 1, cg = blockIdx.x & 1;
    const int row_base = rg * 64;

    if (t < 64) xn_s[t] = 0.f;
    if (t < 512) cn_s[t] = cnorm[cg * 512 + t];
    __syncthreads();

    // ---- stage + convert z tile (64 rows x 128) hi/lo, XOR-swizzled ----
    {
        const float4* zg = reinterpret_cast<const float4*>(z + (size_t)row_base * D);
#pragma unroll
        for (int k = 0; k < 4; ++k) {
            int f = t + k * 512;            // 0..2047
            int r = f >> 5, d4 = f & 31;
            float4 v = zg[f];
            u16 h0 = f2bf(v.x), h1 = f2bf(v.y), h2 = f2bf(v.z), h3 = f2bf(v.w);
            u16 l0 = f2bf(v.x - bf2f(h0)), l1 = f2bf(v.y - bf2f(h1));
            u16 l2 = f2bf(v.z - bf2f(h2)), l3 = f2bf(v.w - bf2f(h3));
            int sb = (r * 256 + d4 * 8) ^ ((r & 7) << 4);
            *reinterpret_cast<ushort4*>((char*)zsh + sb) = make_ushort4(h0, h1, h2, h3);
            *reinterpret_cast<ushort4*>((char*)zsh + 16384 + sb) = make_ushort4(l0, l1, l2, l3);
            atomicAdd(&xn_s[r], v.x * v.x + v.y * v.y + v.z * v.z + v.w * v.w);
        }
    }

    // ---- load this wave's 64 codes into registers (one-time, L2-resident) ----
    bf16x8 ch[4][4], cl[4][4];
    {
        const u16* cbase = frag + (size_t)(cg * 512 + wave * 64) * 256;
#pragma unroll
        for (int nt = 0; nt < 4; ++nt)
#pragma unroll
            for (int kb = 0; kb < 4; ++kb) {
                const u16* p = cbase + (size_t)(nt * 16 + lr) * 256 + kb * 32 + lg * 8;
                ch[nt][kb] = *reinterpret_cast<const bf16x8*>(p);
                cl[nt][kb] = *reinterpret_cast<const bf16x8*>(p + 128);
            }
    }
    __syncthreads();    // z tile ready

    float v1[4], v2[4];
    int i1[4], i2[4];
#pragma unroll
    for (int s = 0; s < 4; ++s) { v1[s] = INFINITY; v2[s] = INFINITY; i1[s] = K; i2[s] = K; }

    const int code0 = cg * 512 + wave * 64;

#pragma unroll
    for (int s = 0; s < 4; ++s) {       // z subchunks of 16 rows; NO barriers
        f32x4 acc[4];
#pragma unroll
        for (int nt = 0; nt < 4; ++nt) { acc[nt][0] = 0.f; acc[nt][1] = 0.f; acc[nt][2] = 0.f; acc[nt][3] = 0.f; }

#pragma unroll
        for (int kb = 0; kb < 4; ++kb) {
            int zrow = s * 16 + lr;     // B-operand col = z-row
            int sb = (zrow * 256 + kb * 64 + lg * 16) ^ ((zrow & 7) << 4);
            bf16x8 zh = *reinterpret_cast<const bf16x8*>((char*)zsh + sb);
            bf16x8 zl = *reinterpret_cast<const bf16x8*>((char*)zsh + 16384 + sb);
#pragma unroll
            for (int nt = 0; nt < 4; ++nt) {
                acc[nt] = __builtin_amdgcn_mfma_f32_16x16x32_bf16(ch[nt][kb], zh, acc[nt], 0, 0, 0);
                acc[nt] = __builtin_amdgcn_mfma_f32_16x16x32_bf16(ch[nt][kb], zl, acc[nt], 0, 0, 0);
                acc[nt] = __builtin_amdgcn_mfma_f32_16x16x32_bf16(cl[nt][kb], zh, acc[nt], 0, 0, 0);
            }
        }

        // epilogue: lane's z-row = s*16+lr; codes code0 + nt*16 + lg*4 + {0..3}
        const int myrow = row_base + s * 16 + lr;
        const float xn = xn_s[s * 16 + lr];
        float* orow = out_dist + (size_t)myrow * K + code0 + lg * 4;
#pragma unroll
        for (int nt = 0; nt < 4; ++nt) {
            float4 cn4 = *reinterpret_cast<const float4*>(&cn_s[wave * 64 + nt * 16 + lg * 4]);
            int cb0 = code0 + nt * 16 + lg * 4;
            float d0 = fmaf(-2.f, acc[nt][0], xn + cn4.x);
            float d1 = fmaf(-2.f, acc[nt][1], xn + cn4.y);
            float d2 = fmaf(-2.f, acc[nt][2], xn + cn4.z);
            float d3 = fmaf(-2.f, acc[nt][3], xn + cn4.w);
            if (d0 < v1[s]) { v2[s] = v1[s]; i2[s] = i1[s]; v1[s] = d0; i1[s] = cb0; }
            else if (d0 < v2[s]) { v2[s] = d0; i2[s] = cb0; }
            if (d1 < v1[s]) { v2[s] = v1[s]; i2[s] = i1[s]; v1[s] = d1; i1[s] = cb0 + 1; }
            else if (d1 < v2[s]) { v2[s] = d1; i2[s] = cb0 + 1; }
            if (d2 < v1[s]) { v2[s] = v1[s]; i2[s] = i1[s]; v1[s] = d2; i1[s] = cb0 + 2; }
            else if (d2 < v2[s]) { v2[s] = d2; i2[s] = cb0 + 2; }
            if (d3 < v1[s]) { v2[s] = v1[s]; i2[s] = i1[s]; v1[s] = d3; i1[s] = cb0 + 3; }
            else if (d3 < v2[s]) { v2[s] = d3; i2[s] = cb0 + 3; }
            f32x4 dv = {d0, d1, d2, d3};
            __builtin_nontemporal_store(dv, reinterpret_cast<f32x4*>(orow + nt * 16));
        }
    }

    // ---- cross-lane merge (lg groups share same z-row): xor 16, 32 ----
#pragma unroll
    for (int s = 0; s < 4; ++s) {
#pragma unroll
        for (int m = 16; m <= 32; m <<= 1) {
            float bv1 = __shfl_xor(v1[s], m), bv2 = __shfl_xor(v2[s], m);
            int bi1 = __shfl_xor(i1[s], m), bi2 = __shfl_xor(i2[s], m);
            t2merge(v1[s], i1[s], v2[s], i2[s], bv1, bi1, bv2, bi2);
        }
    }

    __syncthreads();   // everyone done reading zsh -> reuse as scratch
    float4* scr = reinterpret_cast<float4*>(zsh);   // [64 rows][8 waves]
    if (lane < 16) {
#pragma unroll
        for (int s = 0; s < 4; ++s) {
            int row = s * 16 + lane;
            float4 p;
            p.x = v1[s]; p.y = v2[s];
            p.z = __int_as_float(i1[s]); p.w = __int_as_float(i2[s]);
            scr[row * 8 + wave] = p;
        }
    }
    __syncthreads();

    if (t < 64) {
        float bv = INFINITY, sv = INFINITY;
        int bi = K, si = K;
        for (int w = 0; w < 8; ++w) {
            float4 p = scr[t * 8 + w];
            t2merge(bv, bi, sv, si, p.x, __float_as_int(p.z), p.y, __float_as_int(p.w));
        }
        float4 o;
        o.x = bv; o.y = sv;
        o.z = __int_as_float(bi); o.w = __int_as_float(si);
        part[(size_t)(row_base + t) * 2 + cg] = o;
    }
}

// merge 2 code-group partials, fp64-refine top-2, write idx/zq/hist/loss
__global__ __launch_bounds__(256)
void vq_merge(const float* __restrict__ z, const float* __restrict__ codebook,
              const float4* __restrict__ part, int* __restrict__ hist,
              float* __restrict__ loss_accum, float* __restrict__ out_zq,
              float* __restrict__ out_idx) {
    __shared__ int best_s[64];
    const int t = threadIdx.x;
    const int lane = t & 63;
    const int row0 = blockIdx.x * 64;
    const int rr = t >> 2, t4 = t & 3;
    const int row = row0 + rr;

    float4 pa = part[(size_t)row * 2];
    float4 pb = part[(size_t)row * 2 + 1];
    float v1 = pa.x, v2 = pa.y;
    int i1 = __float_as_int(pa.z), i2 = __float_as_int(pa.w);
    t2merge(v1, i1, v2, i2, pb.x, __float_as_int(pb.z), pb.y, __float_as_int(pb.w));
    const int bi = i1, si = i2;

    const float4* zr = reinterpret_cast<const float4*>(z + (size_t)row * D);
    const float4* c1 = reinterpret_cast<const float4*>(codebook + (size_t)bi * D);
    const float4* c2 = reinterpret_cast<const float4*>(codebook + (size_t)si * D);
    double dd1 = 0.0, dd2 = 0.0;
#pragma unroll
    for (int j = 0; j < 8; ++j) {
        float4 xv = zr[t4 * 8 + j];
        float4 a = c1[t4 * 8 + j];
        float4 b = c2[t4 * 8 + j];
        double e;
        e = (double)xv.x - (double)a.x; dd1 += e * e;
        e = (double)xv.y - (double)a.y; dd1 += e * e;
        e = (double)xv.z - (double)a.z; dd1 += e * e;
        e = (double)xv.w - (double)a.w; dd1 += e * e;
        e = (double)xv.x - (double)b.x; dd2 += e * e;
        e = (double)xv.y - (double)b.y; dd2 += e * e;
        e = (double)xv.z - (double)b.z; dd2 += e * e;
        e = (double)xv.w - (double)b.w; dd2 += e * e;
    }
    dd1 += __shfl_xor(dd1, 1); dd1 += __shfl_xor(dd1, 2);
    dd2 += __shfl_xor(dd2, 1); dd2 += __shfl_xor(dd2, 2);
    float lossv = 0.f;
    if (t4 == 0) {
        int fi = bi; double dmin = dd1;
        if (dd2 < dd1 || (dd2 == dd1 && si < bi)) { fi = si; dmin = dd2; }
        best_s[rr] = fi;
        out_idx[row] = (float)fi;
        atomicAdd(&hist[fi], 1);
        lossv = (float)dmin;
    }
#pragma unroll
    for (int o = 32; o > 0; o >>= 1) lossv += __shfl_down(lossv, o);
    if (lane == 0) atomicAdd(loss_accum, lossv);
    __syncthreads();

    const float4* cb4 = reinterpret_cast<const float4*>(codebook);
    float4* zq4 = reinterpret_cast<float4*>(out_zq + (size_t)row0 * D);
#pragma unroll
    for (int k = 0; k < 8; ++k) {
        int f = t + k * 256;            // 0..2047
        int r = f >> 5, d4 = f & 31;
        float4 q = cb4[(size_t)best_s[r] * 32 + d4];
        f32x4 qv = {q.x, q.y, q.z, q.w};
        __builtin_nontemporal_store(qv, reinterpret_cast<f32x4*>(&zq4[f]));
    }
}

// ---------------- FALLBACK PATH (round-4, proven) ----------------
#define BM 32
#define BN 32
#define NCH (K / BN)
#define CHB 16384

__global__ void prep_cb(const float* __restrict__ cb, u16* __restrict__ frag,
                        float* __restrict__ cnorm) {
    int tid = blockIdx.x * blockDim.x + threadIdx.x;
    int code = tid >> 5, d4 = tid & 31;
    float4 v = reinterpret_cast<const float4*>(cb)[tid];
    u16 h0 = f2bf(v.x), h1 = f2bf(v.y), h2 = f2bf(v.z), h3 = f2bf(v.w);
    u16 l0 = f2bf(v.x - bf2f(h0)), l1 = f2bf(v.y - bf2f(h1));
    u16 l2 = f2bf(v.z - bf2f(h2)), l3 = f2bf(v.w - bf2f(h3));
    int c = code >> 5, row = code & 31;
    int sb = (row * 256 + d4 * 8) ^ ((row & 7) << 4);
    char* base = (char*)frag + (size_t)c * CHB;
    *reinterpret_cast<ushort4*>(base + sb) = make_ushort4(h0, h1, h2, h3);
    *reinterpret_cast<ushort4*>(base + 8192 + sb) = make_ushort4(l0, l1, l2, l3);
    float s = v.x * v.x + v.y * v.y + v.z * v.z + v.w * v.w;
#pragma unroll
    for (int m = 1; m <= 16; m <<= 1) s += __shfl_xor(s, m);
    if (d4 == 0) cnorm[code] = s;
}

__global__ __launch_bounds__(256, 4)
void vq_main(const float* __restrict__ z, const float* __restrict__ codebook,
             const float* __restrict__ cnorm, const u16* __restrict__ frag,
             int* __restrict__ hist, float* __restrict__ loss_accum,
             float* __restrict__ out_zq, float* __restrict__ out_idx,
             float* __restrict__ out_dist) {
    __shared__ u16 Bsh[2][8192];
    __shared__ float cn_s[K];
    __shared__ float xn_s[BM];
    __shared__ int bi_s[BM], si_s[BM], best_s[BM];

    const int t = threadIdx.x;
    const int lane = t & 63;
    const int wave = t >> 6;
    const int lr = lane & 15, lg = lane >> 4;
    const int rowgrp = wave & 1, colhalf = wave >> 1;
    const int row_base = blockIdx.x * BM;

    if (t < BM) xn_s[t] = 0.f;
#pragma unroll
    for (int k = 0; k < 4; ++k) cn_s[t + k * 256] = cnorm[t + k * 256];
    __syncthreads();

    {
        const float4* zg = reinterpret_cast<const float4*>(z + (size_t)row_base * D);
#pragma unroll
        for (int k = 0; k < 4; ++k) {
            int f = t + k * 256;
            int r = f >> 5, d4 = f & 31;
            float4 v = zg[f];
            u16 h0 = f2bf(v.x), h1 = f2bf(v.y), h2 = f2bf(v.z), h3 = f2bf(v.w);
            u16 l0 = f2bf(v.x - bf2f(h0)), l1 = f2bf(v.y - bf2f(h1));
            u16 l2 = f2bf(v.z - bf2f(h2)), l3 = f2bf(v.w - bf2f(h3));
            int sb = (r * 256 + d4 * 8) ^ ((r & 7) << 4);
            *reinterpret_cast<ushort4*>((char*)Bsh + sb) = make_ushort4(h0, h1, h2, h3);
            *reinterpret_cast<ushort4*>((char*)Bsh + 8192 + sb) = make_ushort4(l0, l1, l2, l3);
            atomicAdd(&xn_s[r], v.x * v.x + v.y * v.y + v.z * v.z + v.w * v.w);
        }
    }
    __syncthreads();

    const int arow = rowgrp * 16 + lr;
    bf16x8 zh[4], zl[4];
#pragma unroll
    for (int kb = 0; kb < 4; ++kb) {
        int sb = (arow * 256 + kb * 64 + lg * 16) ^ ((arow & 7) << 4);
        zh[kb] = *reinterpret_cast<const bf16x8*>((char*)Bsh + sb);
        zl[kb] = *reinterpret_cast<const bf16x8*>((char*)Bsh + 8192 + sb);
    }
    const float xn = xn_s[arow];

    const char* fsrc = (const char*)frag + t * 16;
    {
        char* dst = (char*)Bsh + 16384 + t * 16;
#pragma unroll
        for (int it = 0; it < 4; ++it) gll16(fsrc + it * 4096, dst + it * 4096);
    }
    __syncthreads();

    float v1 = INFINITY, v2 = INFINITY;
    int i1 = K, i2 = K;
    int cur = 1;
    const int myrow = row_base + rowgrp * 16 + lr;
    float* orow = out_dist + (size_t)myrow * K + colhalf * 16 + lg * 4;
    const int crow = colhalf * 16 + lr;

    for (int c = 0; c < NCH; ++c) {
        if (c < NCH - 1) {
            const char* src = fsrc + (size_t)(c + 1) * CHB;
            char* dst = (char*)Bsh + (cur ^ 1) * 16384 + t * 16;
#pragma unroll
            for (int it = 0; it < 4; ++it) gll16(src + it * 4096, dst + it * 4096);
        }

        const char* bb = (const char*)Bsh + cur * 16384;
        f32x4 acc = {0.f, 0.f, 0.f, 0.f};
#pragma unroll
        for (int kb = 0; kb < 4; ++kb) {
            int sb = (crow * 256 + kb * 64 + lg * 16) ^ ((crow & 7) << 4);
            bf16x8 chh = *reinterpret_cast<const bf16x8*>(bb + sb);
            bf16x8 cll = *reinterpret_cast<const bf16x8*>(bb + 8192 + sb);
            acc = __builtin_amdgcn_mfma_f32_16x16x32_bf16(chh, zh[kb], acc, 0, 0, 0);
            acc = __builtin_amdgcn_mfma_f32_16x16x32_bf16(chh, zl[kb], acc, 0, 0, 0);
            acc = __builtin_amdgcn_mfma_f32_16x16x32_bf16(cll, zh[kb], acc, 0, 0, 0);
        }

        const int cbase = c * BN + colhalf * 16 + lg * 4;
        float4 cn4 = *reinterpret_cast<const float4*>(&cn_s[cbase]);
        float d0 = fmaf(-2.f, acc[0], xn + cn4.x);
        float d1 = fmaf(-2.f, acc[1], xn + cn4.y);
        float d2 = fmaf(-2.f, acc[2], xn + cn4.z);
        float d3 = fmaf(-2.f, acc[3], xn + cn4.w);
        if (d0 < v1) { v2 = v1; i2 = i1; v1 = d0; i1 = cbase; }
        else if (d0 < v2) { v2 = d0; i2 = cbase; }
        if (d1 < v1) { v2 = v1; i2 = i1; v1 = d1; i1 = cbase + 1; }
        else if (d1 < v2) { v2 = d1; i2 = cbase + 1; }
        if (d2 < v1) { v2 = v1; i2 = i1; v1 = d2; i1 = cbase + 2; }
        else if (d2 < v2) { v2 = d2; i2 = cbase + 2; }
        if (d3 < v1) { v2 = v1; i2 = i1; v1 = d3; i1 = cbase + 3; }
        else if (d3 < v2) { v2 = d3; i2 = cbase + 3; }
        *reinterpret_cast<float4*>(orow + (size_t)c * BN) = make_float4(d0, d1, d2, d3);

        __syncthreads();
        cur ^= 1;
    }

    float* rv1 = reinterpret_cast<float*>(Bsh);
    float* rv2 = rv1 + 256;
    int* ri1 = reinterpret_cast<int*>(rv2 + 256);
    int* ri2 = ri1 + 256;
    {
        const int slot = colhalf * 4 + lg;
        const int rr = rowgrp * 16 + lr;
        rv1[slot * 32 + rr] = v1;
        rv2[slot * 32 + rr] = v2;
        ri1[slot * 32 + rr] = i1;
        ri2[slot * 32 + rr] = i2;
    }
    __syncthreads();

    if (t < BM) {
        float bv = INFINITY, sv = INFINITY;
        int bi = K, si = K;
        for (int s = 0; s < 8; ++s) {
            t2merge(bv, bi, sv, si, rv1[s * 32 + t], ri1[s * 32 + t], rv2[s * 32 + t], ri2[s * 32 + t]);
        }
        bi_s[t] = bi;
        si_s[t] = si;
    }
    __syncthreads();

    float lossv = 0.f;
    if (t < 128) {
        const int rr = t >> 2, t4 = t & 3;
        const int bi = bi_s[rr], si = si_s[rr];
        const float4* zr = reinterpret_cast<const float4*>(z + (size_t)(row_base + rr) * D);
        const float4* c1 = reinterpret_cast<const float4*>(codebook + (size_t)bi * D);
        const float4* c2 = reinterpret_cast<const float4*>(codebook + (size_t)si * D);
        double dd1 = 0.0, dd2 = 0.0;
#pragma unroll
        for (int j = 0; j < 8; ++j) {
            float4 xv = zr[t4 * 8 + j];
            float4 a = c1[t4 * 8 + j];
            float4 b = c2[t4 * 8 + j];
            double e;
            e = (double)xv.x - (double)a.x; dd1 += e * e;
            e = (double)xv.y - (double)a.y; dd1 += e * e;
            e = (double)xv.z - (double)a.z; dd1 += e * e;
            e = (double)xv.w - (double)a.w; dd1 += e * e;
            e = (double)xv.x - (double)b.x; dd2 += e * e;
            e = (double)xv.y - (double)b.y; dd2 += e * e;
            e = (double)xv.z - (double)b.z; dd2 += e * e;
            e = (double)xv.w - (double)b.w; dd2 += e * e;
        }
        dd1 += __shfl_xor(dd1, 1); dd1 += __shfl_xor(dd1, 2);
        dd2 += __shfl_xor(dd2, 1); dd2 += __shfl_xor(dd2, 2);
        if (t4 == 0) {
            int fi = bi; double dmin = dd1;
            if (dd2 < dd1 || (dd2 == dd1 && si < bi)) { fi = si; dmin = dd2; }
            best_s[rr] = fi;
            out_idx[row_base + rr] = (float)fi;
            atomicAdd(&hist[fi], 1);
            lossv = (float)dmin;
        }
    }
#pragma unroll
    for (int o = 32; o > 0; o >>= 1) lossv += __shfl_down(lossv, o);
    if (lane == 0) atomicAdd(loss_accum, lossv);
    __syncthreads();

    {
        const float4* cb4 = reinterpret_cast<const float4*>(codebook);
        float4* zq4 = reinterpret_cast<float4*>(out_zq + (size_t)row_base * D);
#pragma unroll
        for (int k = 0; k < 4; ++k) {
            int f = t + k * 256;
            int r = f >> 5, d4 = f & 31;
            zq4[f] = cb4[(size_t)best_s[r] * 32 + d4];
        }
    }
}

__global__ void vq_finalize(const int* __restrict__ hist, const float* __restrict__ loss_accum,
                            float* __restrict__ out_scalars, int M) {
    __shared__ float red[256];
    int t = threadIdx.x;
    float s = 0.f;
    float invM = 1.0f / (float)M;
#pragma unroll
    for (int k = 0; k < K / 256; ++k) {
        float p = (float)hist[t + k * 256] * invM;
        s += p * logf(p + 1e-10f);
    }
    red[t] = s;
    __syncthreads();
    for (int off = 128; off > 0; off >>= 1) {
        if (t < off) red[t] += red[t + off];
        __syncthreads();
    }
    if (t == 0) {
        float loss = loss_accum[0] / ((float)M * (float)D);
        out_scalars[0] = 0.25f * loss;
        out_scalars[1] = loss;
        out_scalars[2] = expf(-red[0]);
    }
}

extern "C" void kernel_launch(void* const* d_in, const int* in_sizes, int n_in,
                              void* d_out, int out_size, void* d_ws, size_t ws_size,
                              hipStream_t stream) {
    const float* z = (const float*)d_in[0];
    const float* codebook = (const float*)d_in[1];
    int M = in_sizes[0] / D;   // 32768

    float* out = (float*)d_out;
    float* out_zq = out;
    float* out_idx = out + (size_t)M * D;
    float* out_scalars = out_idx + M;
    float* out_dist = out_scalars + 3;

    int* hist = (int*)d_ws;
    float* loss_accum = (float*)((char*)d_ws + 4096);
    float* cnorm = (float*)((char*)d_ws + 8192);
    u16* frag = (u16*)((char*)d_ws + 16384);
    float4* part = (float4*)((char*)d_ws + 540672);

    hipMemsetAsync(d_ws, 0, 8192, stream);
    if (ws_size >= (size_t)540672 + (size_t)M * 32) {
        prep2<<<(K * D / 4) / 256, 256, 0, stream>>>(codebook, frag, cnorm);
        vq_dist<<<(M / 64) * 2, 512, 0, stream>>>(z, frag, cnorm, part, out_dist);
        vq_merge<<<M / 64, 256, 0, stream>>>(z, codebook, part, hist, loss_accum,
                                             out_zq, out_idx);
    } else {
        prep_cb<<<(K * D / 4) / 256, 256, 0, stream>>>(codebook, frag, cnorm);
        vq_main<<<M / BM, 256, 0, stream>>>(z, codebook, cnorm, frag, hist, loss_accum,
                                            out_zq, out_idx, out_dist);
    }
    vq_finalize<<<1, 256, 0, stream>>>(hist, loss_accum, out_scalars, M);
}

// Round 6
// 195.789 us; speedup vs baseline: 2.2761x; 2.2761x over previous
//
#include <hip/hip_runtime.h>
#include <math.h>

#define D 128
#define K 1024

typedef __attribute__((ext_vector_type(8))) short bf16x8;
typedef __attribute__((ext_vector_type(4))) float f32x4;
typedef unsigned short u16;

// ws layout:
// [0,4096)        hist (1024 int)
// [4096,4100)     loss accumulator
// [8192,12288)    cnorm (1024 f32)
// [16384,540672)  frag image (512 KB): code-major [1024][hi128|lo128] u16
// [540672,1589248) top-2 partials: [32768 rows][2 cg] float4 (v1,v2,i1,i2)

__device__ __forceinline__ u16 f2bf(float x) {
    union { float f; unsigned u; } v; v.f = x;
    unsigned r = (v.u + 0x7FFFu + ((v.u >> 16) & 1u)) >> 16;
    return (u16)r;
}
__device__ __forceinline__ float bf2f(u16 b) {
    union { float f; unsigned u; } v; v.u = ((unsigned)b) << 16;
    return v.f;
}
__device__ __forceinline__ void gll16(const void* g, void* l) {
    __builtin_amdgcn_global_load_lds(
        (const __attribute__((address_space(1))) void*)g,
        (__attribute__((address_space(3))) void*)l, 16, 0, 0);
}

__device__ __forceinline__ void t2merge(float& v1, int& i1, float& v2, int& i2,
                                        float bv1, int bi1, float bv2, int bi2) {
    if (bv1 < v1 || (bv1 == v1 && bi1 < i1)) {
        v2 = v1; i2 = i1;
        v1 = bv1; i1 = bi1;
        if (bv2 < v2 || (bv2 == v2 && bi2 < i2)) { v2 = bv2; i2 = bi2; }
    } else {
        if (bv1 < v2 || (bv1 == v2 && bi1 < i2)) { v2 = bv1; i2 = bi1; }
    }
}

// ---------------- MAIN PATH ----------------

// codebook -> code-major bf16 hi/lo fragment image + cnorm
__global__ void prep2(const float* __restrict__ cb, u16* __restrict__ frag,
                      float* __restrict__ cnorm) {
    int tid = blockIdx.x * blockDim.x + threadIdx.x;   // 32768: one float4/thread
    int code = tid >> 5, d4 = tid & 31;
    float4 v = reinterpret_cast<const float4*>(cb)[tid];
    u16 h0 = f2bf(v.x), h1 = f2bf(v.y), h2 = f2bf(v.z), h3 = f2bf(v.w);
    u16 l0 = f2bf(v.x - bf2f(h0)), l1 = f2bf(v.y - bf2f(h1));
    u16 l2 = f2bf(v.z - bf2f(h2)), l3 = f2bf(v.w - bf2f(h3));
    u16* base = frag + (size_t)code * 256;
    *reinterpret_cast<ushort4*>(base + d4 * 4) = make_ushort4(h0, h1, h2, h3);
    *reinterpret_cast<ushort4*>(base + 128 + d4 * 4) = make_ushort4(l0, l1, l2, l3);
    float s = v.x * v.x + v.y * v.y + v.z * v.z + v.w * v.w;
#pragma unroll
    for (int m = 1; m <= 16; m <<= 1) s += __shfl_xor(s, m);
    if (d4 == 0) cnorm[code] = s;
}

// block = 512 thr (8 waves). Block (rg, cg) computes rows rg*64..+63 x codes cg*512..+511.
// Codebook fragments in REGISTERS (64 codes/wave, ~128 VGPR); z tile in LDS.
// NO barriers / NO vmcnt drains in the MFMA+store loop.
__global__ __launch_bounds__(512, 2)   // <-- min 2 waves/EU: VGPR budget 256 (round-5 bug was 8 here)
void vq_dist(const float* __restrict__ z, const u16* __restrict__ frag,
             const float* __restrict__ cnorm, float4* __restrict__ part,
             float* __restrict__ out_dist) {
    __shared__ u16 zsh[16384];      // 32 KB z tile (hi 16K | lo 16K), swizzled
    __shared__ float cn_s[512];
    __shared__ float xn_s[64];

    const int t = threadIdx.x;
    const int lane = t & 63;
    const int wave = t >> 6;        // 0..7
    const int lr = lane & 15, lg = lane >> 4;
    const int rg = blockIdx.x >> 1, cg = blockIdx.x & 1;
    const int row_base = rg * 64;

    if (t < 64) xn_s[t] = 0.f;
    cn_s[t & 511] = cnorm[cg * 512 + (t & 511)];
    __syncthreads();

    // ---- stage + convert z tile (64 rows x 128) hi/lo, XOR-swizzled ----
    {
        const float4* zg = reinterpret_cast<const float4*>(z + (size_t)row_base * D);
#pragma unroll
        for (int k = 0; k < 4; ++k) {
            int f = t + k * 512;            // 0..2047
            int r = f >> 5, d4 = f & 31;
            float4 v = zg[f];
            u16 h0 = f2bf(v.x), h1 = f2bf(v.y), h2 = f2bf(v.z), h3 = f2bf(v.w);
            u16 l0 = f2bf(v.x - bf2f(h0)), l1 = f2bf(v.y - bf2f(h1));
            u16 l2 = f2bf(v.z - bf2f(h2)), l3 = f2bf(v.w - bf2f(h3));
            int sb = (r * 256 + d4 * 8) ^ ((r & 7) << 4);
            *reinterpret_cast<ushort4*>((char*)zsh + sb) = make_ushort4(h0, h1, h2, h3);
            *reinterpret_cast<ushort4*>((char*)zsh + 16384 + sb) = make_ushort4(l0, l1, l2, l3);
            atomicAdd(&xn_s[r], v.x * v.x + v.y * v.y + v.z * v.z + v.w * v.w);
        }
    }

    // ---- load this wave's 64 codes into registers (L2-resident frag image) ----
    bf16x8 ch[4][4], cl[4][4];
    {
        const u16* cbase = frag + (size_t)(cg * 512 + wave * 64) * 256;
#pragma unroll
        for (int nt = 0; nt < 4; ++nt)
#pragma unroll
            for (int kb = 0; kb < 4; ++kb) {
                const u16* p = cbase + (size_t)(nt * 16 + lr) * 256 + kb * 32 + lg * 8;
                ch[nt][kb] = *reinterpret_cast<const bf16x8*>(p);
                cl[nt][kb] = *reinterpret_cast<const bf16x8*>(p + 128);
            }
    }
    __syncthreads();    // z tile ready

    float v1[4], v2[4];
    int i1[4], i2[4];
#pragma unroll
    for (int s = 0; s < 4; ++s) { v1[s] = INFINITY; v2[s] = INFINITY; i1[s] = K; i2[s] = K; }

    const int code0 = cg * 512 + wave * 64;

#pragma unroll
    for (int s = 0; s < 4; ++s) {       // z subchunks of 16 rows; barrier-free
        f32x4 acc[4];
#pragma unroll
        for (int nt = 0; nt < 4; ++nt) { acc[nt][0] = 0.f; acc[nt][1] = 0.f; acc[nt][2] = 0.f; acc[nt][3] = 0.f; }

#pragma unroll
        for (int kb = 0; kb < 4; ++kb) {
            int zrow = s * 16 + lr;     // B-operand col = z-row
            int sb = (zrow * 256 + kb * 64 + lg * 16) ^ ((zrow & 7) << 4);
            bf16x8 zh = *reinterpret_cast<const bf16x8*>((char*)zsh + sb);
            bf16x8 zl = *reinterpret_cast<const bf16x8*>((char*)zsh + 16384 + sb);
#pragma unroll
            for (int nt = 0; nt < 4; ++nt) {
                acc[nt] = __builtin_amdgcn_mfma_f32_16x16x32_bf16(ch[nt][kb], zh, acc[nt], 0, 0, 0);
                acc[nt] = __builtin_amdgcn_mfma_f32_16x16x32_bf16(ch[nt][kb], zl, acc[nt], 0, 0, 0);
                acc[nt] = __builtin_amdgcn_mfma_f32_16x16x32_bf16(cl[nt][kb], zh, acc[nt], 0, 0, 0);
            }
        }

        // epilogue: lane's z-row = s*16+lr; codes code0 + nt*16 + lg*4 + {0..3}
        const int myrow = row_base + s * 16 + lr;
        const float xn = xn_s[s * 16 + lr];
        float* orow = out_dist + (size_t)myrow * K + code0 + lg * 4;
#pragma unroll
        for (int nt = 0; nt < 4; ++nt) {
            float4 cn4 = *reinterpret_cast<const float4*>(&cn_s[wave * 64 + nt * 16 + lg * 4]);
            int cb0 = code0 + nt * 16 + lg * 4;
            float d0 = fmaf(-2.f, acc[nt][0], xn + cn4.x);
            float d1 = fmaf(-2.f, acc[nt][1], xn + cn4.y);
            float d2 = fmaf(-2.f, acc[nt][2], xn + cn4.z);
            float d3 = fmaf(-2.f, acc[nt][3], xn + cn4.w);
            if (d0 < v1[s]) { v2[s] = v1[s]; i2[s] = i1[s]; v1[s] = d0; i1[s] = cb0; }
            else if (d0 < v2[s]) { v2[s] = d0; i2[s] = cb0; }
            if (d1 < v1[s]) { v2[s] = v1[s]; i2[s] = i1[s]; v1[s] = d1; i1[s] = cb0 + 1; }
            else if (d1 < v2[s]) { v2[s] = d1; i2[s] = cb0 + 1; }
            if (d2 < v1[s]) { v2[s] = v1[s]; i2[s] = i1[s]; v1[s] = d2; i1[s] = cb0 + 2; }
            else if (d2 < v2[s]) { v2[s] = d2; i2[s] = cb0 + 2; }
            if (d3 < v1[s]) { v2[s] = v1[s]; i2[s] = i1[s]; v1[s] = d3; i1[s] = cb0 + 3; }
            else if (d3 < v2[s]) { v2[s] = d3; i2[s] = cb0 + 3; }
            f32x4 dv = {d0, d1, d2, d3};
            __builtin_nontemporal_store(dv, reinterpret_cast<f32x4*>(orow + nt * 16));
        }
    }

    // ---- cross-lane merge (4 lg-groups share each z-row): xor 16, 32 ----
#pragma unroll
    for (int s = 0; s < 4; ++s) {
#pragma unroll
        for (int m = 16; m <= 32; m <<= 1) {
            float bv1 = __shfl_xor(v1[s], m), bv2 = __shfl_xor(v2[s], m);
            int bi1 = __shfl_xor(i1[s], m), bi2 = __shfl_xor(i2[s], m);
            t2merge(v1[s], i1[s], v2[s], i2[s], bv1, bi1, bv2, bi2);
        }
    }

    __syncthreads();   // everyone done reading zsh -> reuse as scratch
    float4* scr = reinterpret_cast<float4*>(zsh);   // [64 rows][8 waves]
    if (lane < 16) {
#pragma unroll
        for (int s = 0; s < 4; ++s) {
            int row = s * 16 + lane;
            float4 p;
            p.x = v1[s]; p.y = v2[s];
            p.z = __int_as_float(i1[s]); p.w = __int_as_float(i2[s]);
            scr[row * 8 + wave] = p;
        }
    }
    __syncthreads();

    if (t < 64) {
        float bv = INFINITY, sv = INFINITY;
        int bi = K, si = K;
        for (int w = 0; w < 8; ++w) {
            float4 p = scr[t * 8 + w];
            t2merge(bv, bi, sv, si, p.x, __float_as_int(p.z), p.y, __float_as_int(p.w));
        }
        float4 o;
        o.x = bv; o.y = sv;
        o.z = __int_as_float(bi); o.w = __int_as_float(si);
        part[(size_t)(row_base + t) * 2 + cg] = o;
    }
}

// merge 2 code-group partials, fp64-refine top-2, write idx/zq/hist/loss
__global__ __launch_bounds__(256)
void vq_merge(const float* __restrict__ z, const float* __restrict__ codebook,
              const float4* __restrict__ part, int* __restrict__ hist,
              float* __restrict__ loss_accum, float* __restrict__ out_zq,
              float* __restrict__ out_idx) {
    __shared__ int best_s[64];
    const int t = threadIdx.x;
    const int lane = t & 63;
    const int row0 = blockIdx.x * 64;
    const int rr = t >> 2, t4 = t & 3;
    const int row = row0 + rr;

    float4 pa = part[(size_t)row * 2];
    float4 pb = part[(size_t)row * 2 + 1];
    float v1 = pa.x, v2 = pa.y;
    int i1 = __float_as_int(pa.z), i2 = __float_as_int(pa.w);
    t2merge(v1, i1, v2, i2, pb.x, __float_as_int(pb.z), pb.y, __float_as_int(pb.w));
    const int bi = i1, si = i2;

    const float4* zr = reinterpret_cast<const float4*>(z + (size_t)row * D);
    const float4* c1 = reinterpret_cast<const float4*>(codebook + (size_t)bi * D);
    const float4* c2 = reinterpret_cast<const float4*>(codebook + (size_t)si * D);
    double dd1 = 0.0, dd2 = 0.0;
#pragma unroll
    for (int j = 0; j < 8; ++j) {
        float4 xv = zr[t4 * 8 + j];
        float4 a = c1[t4 * 8 + j];
        float4 b = c2[t4 * 8 + j];
        double e;
        e = (double)xv.x - (double)a.x; dd1 += e * e;
        e = (double)xv.y - (double)a.y; dd1 += e * e;
        e = (double)xv.z - (double)a.z; dd1 += e * e;
        e = (double)xv.w - (double)a.w; dd1 += e * e;
        e = (double)xv.x - (double)b.x; dd2 += e * e;
        e = (double)xv.y - (double)b.y; dd2 += e * e;
        e = (double)xv.z - (double)b.z; dd2 += e * e;
        e = (double)xv.w - (double)b.w; dd2 += e * e;
    }
    dd1 += __shfl_xor(dd1, 1); dd1 += __shfl_xor(dd1, 2);
    dd2 += __shfl_xor(dd2, 1); dd2 += __shfl_xor(dd2, 2);
    float lossv = 0.f;
    if (t4 == 0) {
        int fi = bi; double dmin = dd1;
        if (dd2 < dd1 || (dd2 == dd1 && si < bi)) { fi = si; dmin = dd2; }
        best_s[rr] = fi;
        out_idx[row] = (float)fi;
        atomicAdd(&hist[fi], 1);
        lossv = (float)dmin;
    }
#pragma unroll
    for (int o = 32; o > 0; o >>= 1) lossv += __shfl_down(lossv, o);
    if (lane == 0) atomicAdd(loss_accum, lossv);
    __syncthreads();

    const float4* cb4 = reinterpret_cast<const float4*>(codebook);
    float4* zq4 = reinterpret_cast<float4*>(out_zq + (size_t)row0 * D);
#pragma unroll
    for (int k = 0; k < 8; ++k) {
        int f = t + k * 256;            // 0..2047
        int r = f >> 5, d4 = f & 31;
        float4 q = cb4[(size_t)best_s[r] * 32 + d4];
        f32x4 qv = {q.x, q.y, q.z, q.w};
        __builtin_nontemporal_store(qv, reinterpret_cast<f32x4*>(&zq4[f]));
    }
}

// ---------------- FALLBACK PATH (round-4, proven) ----------------
#define BM 32
#define BN 32
#define NCH (K / BN)
#define CHB 16384

__global__ void prep_cb(const float* __restrict__ cb, u16* __restrict__ frag,
                        float* __restrict__ cnorm) {
    int tid = blockIdx.x * blockDim.x + threadIdx.x;
    int code = tid >> 5, d4 = tid & 31;
    float4 v = reinterpret_cast<const float4*>(cb)[tid];
    u16 h0 = f2bf(v.x), h1 = f2bf(v.y), h2 = f2bf(v.z), h3 = f2bf(v.w);
    u16 l0 = f2bf(v.x - bf2f(h0)), l1 = f2bf(v.y - bf2f(h1));
    u16 l2 = f2bf(v.z - bf2f(h2)), l3 = f2bf(v.w - bf2f(h3));
    int c = code >> 5, row = code & 31;
    int sb = (row * 256 + d4 * 8) ^ ((row & 7) << 4);
    char* base = (char*)frag + (size_t)c * CHB;
    *reinterpret_cast<ushort4*>(base + sb) = make_ushort4(h0, h1, h2, h3);
    *reinterpret_cast<ushort4*>(base + 8192 + sb) = make_ushort4(l0, l1, l2, l3);
    float s = v.x * v.x + v.y * v.y + v.z * v.z + v.w * v.w;
#pragma unroll
    for (int m = 1; m <= 16; m <<= 1) s += __shfl_xor(s, m);
    if (d4 == 0) cnorm[code] = s;
}

__global__ __launch_bounds__(256, 4)
void vq_main(const float* __restrict__ z, const float* __restrict__ codebook,
             const float* __restrict__ cnorm, const u16* __restrict__ frag,
             int* __restrict__ hist, float* __restrict__ loss_accum,
             float* __restrict__ out_zq, float* __restrict__ out_idx,
             float* __restrict__ out_dist) {
    __shared__ u16 Bsh[2][8192];
    __shared__ float cn_s[K];
    __shared__ float xn_s[BM];
    __shared__ int bi_s[BM], si_s[BM], best_s[BM];

    const int t = threadIdx.x;
    const int lane = t & 63;
    const int wave = t >> 6;
    const int lr = lane & 15, lg = lane >> 4;
    const int rowgrp = wave & 1, colhalf = wave >> 1;
    const int row_base = blockIdx.x * BM;

    if (t < BM) xn_s[t] = 0.f;
#pragma unroll
    for (int k = 0; k < 4; ++k) cn_s[t + k * 256] = cnorm[t + k * 256];
    __syncthreads();

    {
        const float4* zg = reinterpret_cast<const float4*>(z + (size_t)row_base * D);
#pragma unroll
        for (int k = 0; k < 4; ++k) {
            int f = t + k * 256;
            int r = f >> 5, d4 = f & 31;
            float4 v = zg[f];
            u16 h0 = f2bf(v.x), h1 = f2bf(v.y), h2 = f2bf(v.z), h3 = f2bf(v.w);
            u16 l0 = f2bf(v.x - bf2f(h0)), l1 = f2bf(v.y - bf2f(h1));
            u16 l2 = f2bf(v.z - bf2f(h2)), l3 = f2bf(v.w - bf2f(h3));
            int sb = (r * 256 + d4 * 8) ^ ((r & 7) << 4);
            *reinterpret_cast<ushort4*>((char*)Bsh + sb) = make_ushort4(h0, h1, h2, h3);
            *reinterpret_cast<ushort4*>((char*)Bsh + 8192 + sb) = make_ushort4(l0, l1, l2, l3);
            atomicAdd(&xn_s[r], v.x * v.x + v.y * v.y + v.z * v.z + v.w * v.w);
        }
    }
    __syncthreads();

    const int arow = rowgrp * 16 + lr;
    bf16x8 zh[4], zl[4];
#pragma unroll
    for (int kb = 0; kb < 4; ++kb) {
        int sb = (arow * 256 + kb * 64 + lg * 16) ^ ((arow & 7) << 4);
        zh[kb] = *reinterpret_cast<const bf16x8*>((char*)Bsh + sb);
        zl[kb] = *reinterpret_cast<const bf16x8*>((char*)Bsh + 8192 + sb);
    }
    const float xn = xn_s[arow];

    const char* fsrc = (const char*)frag + t * 16;
    {
        char* dst = (char*)Bsh + 16384 + t * 16;
#pragma unroll
        for (int it = 0; it < 4; ++it) gll16(fsrc + it * 4096, dst + it * 4096);
    }
    __syncthreads();

    float v1 = INFINITY, v2 = INFINITY;
    int i1 = K, i2 = K;
    int cur = 1;
    const int myrow = row_base + rowgrp * 16 + lr;
    float* orow = out_dist + (size_t)myrow * K + colhalf * 16 + lg * 4;
    const int crow = colhalf * 16 + lr;

    for (int c = 0; c < NCH; ++c) {
        if (c < NCH - 1) {
            const char* src = fsrc + (size_t)(c + 1) * CHB;
            char* dst = (char*)Bsh + (cur ^ 1) * 16384 + t * 16;
#pragma unroll
            for (int it = 0; it < 4; ++it) gll16(src + it * 4096, dst + it * 4096);
        }

        const char* bb = (const char*)Bsh + cur * 16384;
        f32x4 acc = {0.f, 0.f, 0.f, 0.f};
#pragma unroll
        for (int kb = 0; kb < 4; ++kb) {
            int sb = (crow * 256 + kb * 64 + lg * 16) ^ ((crow & 7) << 4);
            bf16x8 chh = *reinterpret_cast<const bf16x8*>(bb + sb);
            bf16x8 cll = *reinterpret_cast<const bf16x8*>(bb + 8192 + sb);
            acc = __builtin_amdgcn_mfma_f32_16x16x32_bf16(chh, zh[kb], acc, 0, 0, 0);
            acc = __builtin_amdgcn_mfma_f32_16x16x32_bf16(chh, zl[kb], acc, 0, 0, 0);
            acc = __builtin_amdgcn_mfma_f32_16x16x32_bf16(cll, zh[kb], acc, 0, 0, 0);
        }

        const int cbase = c * BN + colhalf * 16 + lg * 4;
        float4 cn4 = *reinterpret_cast<const float4*>(&cn_s[cbase]);
        float d0 = fmaf(-2.f, acc[0], xn + cn4.x);
        float d1 = fmaf(-2.f, acc[1], xn + cn4.y);
        float d2 = fmaf(-2.f, acc[2], xn + cn4.z);
        float d3 = fmaf(-2.f, acc[3], xn + cn4.w);
        if (d0 < v1) { v2 = v1; i2 = i1; v1 = d0; i1 = cbase; }
        else if (d0 < v2) { v2 = d0; i2 = cbase; }
        if (d1 < v1) { v2 = v1; i2 = i1; v1 = d1; i1 = cbase + 1; }
        else if (d1 < v2) { v2 = d1; i2 = cbase + 1; }
        if (d2 < v1) { v2 = v1; i2 = i1; v1 = d2; i1 = cbase + 2; }
        else if (d2 < v2) { v2 = d2; i2 = cbase + 2; }
        if (d3 < v1) { v2 = v1; i2 = i1; v1 = d3; i1 = cbase + 3; }
        else if (d3 < v2) { v2 = d3; i2 = cbase + 3; }
        *reinterpret_cast<float4*>(orow + (size_t)c * BN) = make_float4(d0, d1, d2, d3);

        __syncthreads();
        cur ^= 1;
    }

    float* rv1 = reinterpret_cast<float*>(Bsh);
    float* rv2 = rv1 + 256;
    int* ri1 = reinterpret_cast<int*>(rv2 + 256);
    int* ri2 = ri1 + 256;
    {
        const int slot = colhalf * 4 + lg;
        const int rr = rowgrp * 16 + lr;
        rv1[slot * 32 + rr] = v1;
        rv2[slot * 32 + rr] = v2;
        ri1[slot * 32 + rr] = i1;
        ri2[slot * 32 + rr] = i2;
    }
    __syncthreads();

    if (t < BM) {
        float bv = INFINITY, sv = INFINITY;
        int bi = K, si = K;
        for (int s = 0; s < 8; ++s) {
            t2merge(bv, bi, sv, si, rv1[s * 32 + t], ri1[s * 32 + t], rv2[s * 32 + t], ri2[s * 32 + t]);
        }
        bi_s[t] = bi;
        si_s[t] = si;
    }
    __syncthreads();

    float lossv = 0.f;
    if (t < 128) {
        const int rr = t >> 2, t4 = t & 3;
        const int bi = bi_s[rr], si = si_s[rr];
        const float4* zr = reinterpret_cast<const float4*>(z + (size_t)(row_base + rr) * D);
        const float4* c1 = reinterpret_cast<const float4*>(codebook + (size_t)bi * D);
        const float4* c2 = reinterpret_cast<const float4*>(codebook + (size_t)si * D);
        double dd1 = 0.0, dd2 = 0.0;
#pragma unroll
        for (int j = 0; j < 8; ++j) {
            float4 xv = zr[t4 * 8 + j];
            float4 a = c1[t4 * 8 + j];
            float4 b = c2[t4 * 8 + j];
            double e;
            e = (double)xv.x - (double)a.x; dd1 += e * e;
            e = (double)xv.y - (double)a.y; dd1 += e * e;
            e = (double)xv.z - (double)a.z; dd1 += e * e;
            e = (double)xv.w - (double)a.w; dd1 += e * e;
            e = (double)xv.x - (double)b.x; dd2 += e * e;
            e = (double)xv.y - (double)b.y; dd2 += e * e;
            e = (double)xv.z - (double)b.z; dd2 += e * e;
            e = (double)xv.w - (double)b.w; dd2 += e * e;
        }
        dd1 += __shfl_xor(dd1, 1); dd1 += __shfl_xor(dd1, 2);
        dd2 += __shfl_xor(dd2, 1); dd2 += __shfl_xor(dd2, 2);
        if (t4 == 0) {
            int fi = bi; double dmin = dd1;
            if (dd2 < dd1 || (dd2 == dd1 && si < bi)) { fi = si; dmin = dd2; }
            best_s[rr] = fi;
            out_idx[row_base + rr] = (float)fi;
            atomicAdd(&hist[fi], 1);
            lossv = (float)dmin;
        }
    }
#pragma unroll
    for (int o = 32; o > 0; o >>= 1) lossv += __shfl_down(lossv, o);
    if (lane == 0) atomicAdd(loss_accum, lossv);
    __syncthreads();

    {
        const float4* cb4 = reinterpret_cast<const float4*>(codebook);
        float4* zq4 = reinterpret_cast<float4*>(out_zq + (size_t)row_base * D);
#pragma unroll
        for (int k = 0; k < 4; ++k) {
            int f = t + k * 256;
            int r = f >> 5, d4 = f & 31;
            zq4[f] = cb4[(size_t)best_s[r] * 32 + d4];
        }
    }
}

__global__ void vq_finalize(const int* __restrict__ hist, const float* __restrict__ loss_accum,
                            float* __restrict__ out_scalars, int M) {
    __shared__ float red[256];
    int t = threadIdx.x;
    float s = 0.f;
    float invM = 1.0f / (float)M;
#pragma unroll
    for (int k = 0; k < K / 256; ++k) {
        float p = (float)hist[t + k * 256] * invM;
        s += p * logf(p + 1e-10f);
    }
    red[t] = s;
    __syncthreads();
    for (int off = 128; off > 0; off >>= 1) {
        if (t < off) red[t] += red[t + off];
        __syncthreads();
    }
    if (t == 0) {
        float loss = loss_accum[0] / ((float)M * (float)D);
        out_scalars[0] = 0.25f * loss;
        out_scalars[1] = loss;
        out_scalars[2] = expf(-red[0]);
    }
}

extern "C" void kernel_launch(void* const* d_in, const int* in_sizes, int n_in,
                              void* d_out, int out_size, void* d_ws, size_t ws_size,
                              hipStream_t stream) {
    const float* z = (const float*)d_in[0];
    const float* codebook = (const float*)d_in[1];
    int M = in_sizes[0] / D;   // 32768

    float* out = (float*)d_out;
    float* out_zq = out;
    float* out_idx = out + (size_t)M * D;
    float* out_scalars = out_idx + M;
    float* out_dist = out_scalars + 3;

    int* hist = (int*)d_ws;
    float* loss_accum = (float*)((char*)d_ws + 4096);
    float* cnorm = (float*)((char*)d_ws + 8192);
    u16* frag = (u16*)((char*)d_ws + 16384);
    float4* part = (float4*)((char*)d_ws + 540672);

    hipMemsetAsync(d_ws, 0, 8192, stream);
    if (ws_size >= (size_t)540672 + (size_t)M * 32) {
        prep2<<<(K * D / 4) / 256, 256, 0, stream>>>(codebook, frag, cnorm);
        vq_dist<<<(M / 64) * 2, 512, 0, stream>>>(z, frag, cnorm, part, out_dist);
        vq_merge<<<M / 64, 256, 0, stream>>>(z, codebook, part, hist, loss_accum,
                                             out_zq, out_idx);
    } else {
        prep_cb<<<(K * D / 4) / 256, 256, 0, stream>>>(codebook, frag, cnorm);
        vq_main<<<M / BM, 256, 0, stream>>>(z, codebook, cnorm, frag, hist, loss_accum,
                                            out_zq, out_idx, out_dist);
    }
    vq_finalize<<<1, 256, 0, stream>>>(hist, loss_accum, out_scalars, M);
}

// Round 7
// 114.048 us; speedup vs baseline: 3.9074x; 1.7167x over previous
//
#include <hip/hip_runtime.h>
#include <math.h>

#define D 128
#define K 1024
#define M_TOTAL 32768

typedef __attribute__((ext_vector_type(8))) short bf16x8;
typedef __attribute__((ext_vector_type(4))) float f32x4;
typedef unsigned short u16;

// ws layout:
// [0,4096)        hist (1024 int)
// [4096,4100)     loss accumulator
// [8192,12288)    cnorm (1024 f32)
// [16384,540672)  frag image (512 KB): code-major [1024][hi128|lo128] u16
// [540672,+8MB)   top-2 partials: [16 slots][M rows] float4 (v1,v2,i1,i2)

__device__ __forceinline__ u16 f2bf(float x) {
    union { float f; unsigned u; } v; v.f = x;
    unsigned r = (v.u + 0x7FFFu + ((v.u >> 16) & 1u)) >> 16;
    return (u16)r;
}
__device__ __forceinline__ float bf2f(u16 b) {
    union { float f; unsigned u; } v; v.u = ((unsigned)b) << 16;
    return v.f;
}
__device__ __forceinline__ void gll16(const void* g, void* l) {
    __builtin_amdgcn_global_load_lds(
        (const __attribute__((address_space(1))) void*)g,
        (__attribute__((address_space(3))) void*)l, 16, 0, 0);
}

__device__ __forceinline__ void t2merge(float& v1, int& i1, float& v2, int& i2,
                                        float bv1, int bi1, float bv2, int bi2) {
    if (bv1 < v1 || (bv1 == v1 && bi1 < i1)) {
        v2 = v1; i2 = i1;
        v1 = bv1; i1 = bi1;
        if (bv2 < v2 || (bv2 == v2 && bi2 < i2)) { v2 = bv2; i2 = bi2; }
    } else {
        if (bv1 < v2 || (bv1 == v2 && bi1 < i2)) { v2 = bv1; i2 = bi1; }
    }
}

// ---------------- MAIN PATH ----------------

// codebook -> code-major bf16 hi/lo fragment image + cnorm
__global__ void prep2(const float* __restrict__ cb, u16* __restrict__ frag,
                      float* __restrict__ cnorm) {
    int tid = blockIdx.x * blockDim.x + threadIdx.x;   // 32768: one float4/thread
    int code = tid >> 5, d4 = tid & 31;
    float4 v = reinterpret_cast<const float4*>(cb)[tid];
    u16 h0 = f2bf(v.x), h1 = f2bf(v.y), h2 = f2bf(v.z), h3 = f2bf(v.w);
    u16 l0 = f2bf(v.x - bf2f(h0)), l1 = f2bf(v.y - bf2f(h1));
    u16 l2 = f2bf(v.z - bf2f(h2)), l3 = f2bf(v.w - bf2f(h3));
    u16* base = frag + (size_t)code * 256;
    *reinterpret_cast<ushort4*>(base + d4 * 4) = make_ushort4(h0, h1, h2, h3);
    *reinterpret_cast<ushort4*>(base + 128 + d4 * 4) = make_ushort4(l0, l1, l2, l3);
    float s = v.x * v.x + v.y * v.y + v.z * v.z + v.w * v.w;
#pragma unroll
    for (int m = 1; m <= 16; m <<= 1) s += __shfl_xor(s, m);
    if (d4 == 0) cnorm[code] = s;
}

// block = 512 thr (8 waves). Block (rg, cg): rows rg*128..+127 x codes cg*512..+511.
// Codebook fragments in REGISTERS (64 codes/wave); z tile (128 rows) in LDS.
// s-loop NOT unrolled (unroll-1) to keep register pressure = single-iteration.
// Plain (through-L2) dist stores: L2 assembles full 128B lines (no nt partial-line 2x).
__global__ __launch_bounds__(512, 2)
void vq_dist(const float* __restrict__ z, const u16* __restrict__ frag,
             const float* __restrict__ cnorm, float4* __restrict__ part,
             float* __restrict__ out_dist) {
    __shared__ u16 zsh[32768];      // 64 KB z tile: hi 32K | lo 32K, XOR-swizzled
    __shared__ float cn_s[512];
    __shared__ float xn_s[128];

    const int t = threadIdx.x;
    const int lane = t & 63;
    const int wave = t >> 6;        // 0..7
    const int lr = lane & 15, lg = lane >> 4;
    const int rg = blockIdx.x >> 1, cg = blockIdx.x & 1;
    const int row_base = rg * 128;

    if (t < 128) xn_s[t] = 0.f;
    cn_s[t] = cnorm[cg * 512 + t];   // t<512 covers all
    __syncthreads();

    // ---- stage + convert z tile (128 rows x 128) hi/lo, XOR-swizzled ----
    {
        const float4* zg = reinterpret_cast<const float4*>(z + (size_t)row_base * D);
#pragma unroll
        for (int k = 0; k < 8; ++k) {
            int f = t + k * 512;            // 0..4095
            int r = f >> 5, d4 = f & 31;
            float4 v = zg[f];
            u16 h0 = f2bf(v.x), h1 = f2bf(v.y), h2 = f2bf(v.z), h3 = f2bf(v.w);
            u16 l0 = f2bf(v.x - bf2f(h0)), l1 = f2bf(v.y - bf2f(h1));
            u16 l2 = f2bf(v.z - bf2f(h2)), l3 = f2bf(v.w - bf2f(h3));
            int sb = (r * 256 + d4 * 8) ^ ((r & 7) << 4);
            *reinterpret_cast<ushort4*>((char*)zsh + sb) = make_ushort4(h0, h1, h2, h3);
            *reinterpret_cast<ushort4*>((char*)zsh + 32768 + sb) = make_ushort4(l0, l1, l2, l3);
            atomicAdd(&xn_s[r], v.x * v.x + v.y * v.y + v.z * v.z + v.w * v.w);
        }
    }

    // ---- load this wave's 64 codes into registers (L2/L3-resident frag image) ----
    bf16x8 ch[4][4], cl[4][4];
    {
        const u16* cbase = frag + (size_t)(cg * 512 + wave * 64) * 256;
#pragma unroll
        for (int nt = 0; nt < 4; ++nt)
#pragma unroll
            for (int kb = 0; kb < 4; ++kb) {
                const u16* p = cbase + (size_t)(nt * 16 + lr) * 256 + kb * 32 + lg * 8;
                ch[nt][kb] = *reinterpret_cast<const bf16x8*>(p);
                cl[nt][kb] = *reinterpret_cast<const bf16x8*>(p + 128);
            }
    }
    __syncthreads();    // z tile ready

    const int code0 = cg * 512 + wave * 64;

#pragma unroll 1
    for (int s = 0; s < 8; ++s) {       // z subchunks of 16 rows; barrier-free
        f32x4 acc[4];
#pragma unroll
        for (int nt = 0; nt < 4; ++nt) { acc[nt][0] = 0.f; acc[nt][1] = 0.f; acc[nt][2] = 0.f; acc[nt][3] = 0.f; }

        const int zrow = s * 16 + lr;   // B-operand col = z-row
#pragma unroll
        for (int kb = 0; kb < 4; ++kb) {
            int sb = (zrow * 256 + kb * 64 + lg * 16) ^ ((zrow & 7) << 4);
            bf16x8 zh = *reinterpret_cast<const bf16x8*>((char*)zsh + sb);
            bf16x8 zl = *reinterpret_cast<const bf16x8*>((char*)zsh + 32768 + sb);
#pragma unroll
            for (int nt = 0; nt < 4; ++nt) {
                acc[nt] = __builtin_amdgcn_mfma_f32_16x16x32_bf16(ch[nt][kb], zh, acc[nt], 0, 0, 0);
                acc[nt] = __builtin_amdgcn_mfma_f32_16x16x32_bf16(ch[nt][kb], zl, acc[nt], 0, 0, 0);
                acc[nt] = __builtin_amdgcn_mfma_f32_16x16x32_bf16(cl[nt][kb], zh, acc[nt], 0, 0, 0);
            }
        }

        // epilogue: lane's z-row = s*16+lr; codes code0 + nt*16 + lg*4 + {0..3}
        const int myrow = row_base + s * 16 + lr;
        const float xn = xn_s[s * 16 + lr];
        float* orow = out_dist + (size_t)myrow * K + code0 + lg * 4;
        float v1 = INFINITY, v2 = INFINITY;
        int i1 = K, i2 = K;
#pragma unroll
        for (int nt = 0; nt < 4; ++nt) {
            float4 cn4 = *reinterpret_cast<const float4*>(&cn_s[wave * 64 + nt * 16 + lg * 4]);
            int cb0 = code0 + nt * 16 + lg * 4;
            float d0 = fmaf(-2.f, acc[nt][0], xn + cn4.x);
            float d1 = fmaf(-2.f, acc[nt][1], xn + cn4.y);
            float d2 = fmaf(-2.f, acc[nt][2], xn + cn4.z);
            float d3 = fmaf(-2.f, acc[nt][3], xn + cn4.w);
            if (d0 < v1) { v2 = v1; i2 = i1; v1 = d0; i1 = cb0; }
            else if (d0 < v2) { v2 = d0; i2 = cb0; }
            if (d1 < v1) { v2 = v1; i2 = i1; v1 = d1; i1 = cb0 + 1; }
            else if (d1 < v2) { v2 = d1; i2 = cb0 + 1; }
            if (d2 < v1) { v2 = v1; i2 = i1; v1 = d2; i1 = cb0 + 2; }
            else if (d2 < v2) { v2 = d2; i2 = cb0 + 2; }
            if (d3 < v1) { v2 = v1; i2 = i1; v1 = d3; i1 = cb0 + 3; }
            else if (d3 < v2) { v2 = d3; i2 = cb0 + 3; }
            f32x4 dv = {d0, d1, d2, d3};
            *reinterpret_cast<f32x4*>(orow + nt * 16) = dv;   // plain store: L2 line-assembly
        }

        // per-s top-2 flush: merge across lg groups (lanes sharing lr), then 16 lanes write
#pragma unroll
        for (int m = 16; m <= 32; m <<= 1) {
            float bv1 = __shfl_xor(v1, m), bv2 = __shfl_xor(v2, m);
            int bi1 = __shfl_xor(i1, m), bi2 = __shfl_xor(i2, m);
            t2merge(v1, i1, v2, i2, bv1, bi1, bv2, bi2);
        }
        if (lane < 16) {
            float4 p;
            p.x = v1; p.y = v2;
            p.z = __int_as_float(i1); p.w = __int_as_float(i2);
            part[(size_t)(cg * 8 + wave) * M_TOTAL + (row_base + s * 16 + lane)] = p;
        }
    }
}

// merge 16 slot partials/row, fp64-refine top-2, write idx/zq/hist/loss
__global__ __launch_bounds__(256)
void vq_merge(const float* __restrict__ z, const float* __restrict__ codebook,
              const float4* __restrict__ part, int* __restrict__ hist,
              float* __restrict__ loss_accum, float* __restrict__ out_zq,
              float* __restrict__ out_idx) {
    __shared__ int best_s[64];
    const int t = threadIdx.x;
    const int lane = t & 63;
    const int row0 = blockIdx.x * 64;
    const int rr = t >> 2, t4 = t & 3;
    const int row = row0 + rr;

    float v1 = INFINITY, v2 = INFINITY;
    int i1 = K, i2 = K;
#pragma unroll
    for (int j = 0; j < 4; ++j) {
        int slot = t4 * 4 + j;
        float4 p = part[(size_t)slot * M_TOTAL + row];
        t2merge(v1, i1, v2, i2, p.x, __float_as_int(p.z), p.y, __float_as_int(p.w));
    }
#pragma unroll
    for (int m = 1; m <= 2; m <<= 1) {
        float bv1 = __shfl_xor(v1, m), bv2 = __shfl_xor(v2, m);
        int bi1 = __shfl_xor(i1, m), bi2 = __shfl_xor(i2, m);
        t2merge(v1, i1, v2, i2, bv1, bi1, bv2, bi2);
    }
    const int bi = i1, si = i2;

    const float4* zr = reinterpret_cast<const float4*>(z + (size_t)row * D);
    const float4* c1 = reinterpret_cast<const float4*>(codebook + (size_t)bi * D);
    const float4* c2 = reinterpret_cast<const float4*>(codebook + (size_t)si * D);
    double dd1 = 0.0, dd2 = 0.0;
#pragma unroll
    for (int j = 0; j < 8; ++j) {
        float4 xv = zr[t4 * 8 + j];
        float4 a = c1[t4 * 8 + j];
        float4 b = c2[t4 * 8 + j];
        double e;
        e = (double)xv.x - (double)a.x; dd1 += e * e;
        e = (double)xv.y - (double)a.y; dd1 += e * e;
        e = (double)xv.z - (double)a.z; dd1 += e * e;
        e = (double)xv.w - (double)a.w; dd1 += e * e;
        e = (double)xv.x - (double)b.x; dd2 += e * e;
        e = (double)xv.y - (double)b.y; dd2 += e * e;
        e = (double)xv.z - (double)b.z; dd2 += e * e;
        e = (double)xv.w - (double)b.w; dd2 += e * e;
    }
    dd1 += __shfl_xor(dd1, 1); dd1 += __shfl_xor(dd1, 2);
    dd2 += __shfl_xor(dd2, 1); dd2 += __shfl_xor(dd2, 2);
    float lossv = 0.f;
    if (t4 == 0) {
        int fi = bi; double dmin = dd1;
        if (dd2 < dd1 || (dd2 == dd1 && si < bi)) { fi = si; dmin = dd2; }
        best_s[rr] = fi;
        out_idx[row] = (float)fi;
        atomicAdd(&hist[fi], 1);
        lossv = (float)dmin;
    }
#pragma unroll
    for (int o = 32; o > 0; o >>= 1) lossv += __shfl_down(lossv, o);
    if (lane == 0) atomicAdd(loss_accum, lossv);
    __syncthreads();

    const float4* cb4 = reinterpret_cast<const float4*>(codebook);
    float4* zq4 = reinterpret_cast<float4*>(out_zq + (size_t)row0 * D);
#pragma unroll
    for (int k = 0; k < 8; ++k) {
        int f = t + k * 256;            // 0..2047
        int r = f >> 5, d4 = f & 31;
        zq4[f] = cb4[(size_t)best_s[r] * 32 + d4];
    }
}

// ---------------- FALLBACK PATH (round-4, proven) ----------------
#define BM 32
#define BN 32
#define NCH (K / BN)
#define CHB 16384

__global__ void prep_cb(const float* __restrict__ cb, u16* __restrict__ frag,
                        float* __restrict__ cnorm) {
    int tid = blockIdx.x * blockDim.x + threadIdx.x;
    int code = tid >> 5, d4 = tid & 31;
    float4 v = reinterpret_cast<const float4*>(cb)[tid];
    u16 h0 = f2bf(v.x), h1 = f2bf(v.y), h2 = f2bf(v.z), h3 = f2bf(v.w);
    u16 l0 = f2bf(v.x - bf2f(h0)), l1 = f2bf(v.y - bf2f(h1));
    u16 l2 = f2bf(v.z - bf2f(h2)), l3 = f2bf(v.w - bf2f(h3));
    int c = code >> 5, row = code & 31;
    int sb = (row * 256 + d4 * 8) ^ ((row & 7) << 4);
    char* base = (char*)frag + (size_t)c * CHB;
    *reinterpret_cast<ushort4*>(base + sb) = make_ushort4(h0, h1, h2, h3);
    *reinterpret_cast<ushort4*>(base + 8192 + sb) = make_ushort4(l0, l1, l2, l3);
    float s = v.x * v.x + v.y * v.y + v.z * v.z + v.w * v.w;
#pragma unroll
    for (int m = 1; m <= 16; m <<= 1) s += __shfl_xor(s, m);
    if (d4 == 0) cnorm[code] = s;
}

__global__ __launch_bounds__(256, 4)
void vq_main(const float* __restrict__ z, const float* __restrict__ codebook,
             const float* __restrict__ cnorm, const u16* __restrict__ frag,
             int* __restrict__ hist, float* __restrict__ loss_accum,
             float* __restrict__ out_zq, float* __restrict__ out_idx,
             float* __restrict__ out_dist) {
    __shared__ u16 Bsh[2][8192];
    __shared__ float cn_s[K];
    __shared__ float xn_s[BM];
    __shared__ int bi_s[BM], si_s[BM], best_s[BM];

    const int t = threadIdx.x;
    const int lane = t & 63;
    const int wave = t >> 6;
    const int lr = lane & 15, lg = lane >> 4;
    const int rowgrp = wave & 1, colhalf = wave >> 1;
    const int row_base = blockIdx.x * BM;

    if (t < BM) xn_s[t] = 0.f;
#pragma unroll
    for (int k = 0; k < 4; ++k) cn_s[t + k * 256] = cnorm[t + k * 256];
    __syncthreads();

    {
        const float4* zg = reinterpret_cast<const float4*>(z + (size_t)row_base * D);
#pragma unroll
        for (int k = 0; k < 4; ++k) {
            int f = t + k * 256;
            int r = f >> 5, d4 = f & 31;
            float4 v = zg[f];
            u16 h0 = f2bf(v.x), h1 = f2bf(v.y), h2 = f2bf(v.z), h3 = f2bf(v.w);
            u16 l0 = f2bf(v.x - bf2f(h0)), l1 = f2bf(v.y - bf2f(h1));
            u16 l2 = f2bf(v.z - bf2f(h2)), l3 = f2bf(v.w - bf2f(h3));
            int sb = (r * 256 + d4 * 8) ^ ((r & 7) << 4);
            *reinterpret_cast<ushort4*>((char*)Bsh + sb) = make_ushort4(h0, h1, h2, h3);
            *reinterpret_cast<ushort4*>((char*)Bsh + 8192 + sb) = make_ushort4(l0, l1, l2, l3);
            atomicAdd(&xn_s[r], v.x * v.x + v.y * v.y + v.z * v.z + v.w * v.w);
        }
    }
    __syncthreads();

    const int arow = rowgrp * 16 + lr;
    bf16x8 zh[4], zl[4];
#pragma unroll
    for (int kb = 0; kb < 4; ++kb) {
        int sb = (arow * 256 + kb * 64 + lg * 16) ^ ((arow & 7) << 4);
        zh[kb] = *reinterpret_cast<const bf16x8*>((char*)Bsh + sb);
        zl[kb] = *reinterpret_cast<const bf16x8*>((char*)Bsh + 8192 + sb);
    }
    const float xn = xn_s[arow];

    const char* fsrc = (const char*)frag + t * 16;
    {
        char* dst = (char*)Bsh + 16384 + t * 16;
#pragma unroll
        for (int it = 0; it < 4; ++it) gll16(fsrc + it * 4096, dst + it * 4096);
    }
    __syncthreads();

    float v1 = INFINITY, v2 = INFINITY;
    int i1 = K, i2 = K;
    int cur = 1;
    const int myrow = row_base + rowgrp * 16 + lr;
    float* orow = out_dist + (size_t)myrow * K + colhalf * 16 + lg * 4;
    const int crow = colhalf * 16 + lr;

    for (int c = 0; c < NCH; ++c) {
        if (c < NCH - 1) {
            const char* src = fsrc + (size_t)(c + 1) * CHB;
            char* dst = (char*)Bsh + (cur ^ 1) * 16384 + t * 16;
#pragma unroll
            for (int it = 0; it < 4; ++it) gll16(src + it * 4096, dst + it * 4096);
        }

        const char* bb = (const char*)Bsh + cur * 16384;
        f32x4 acc = {0.f, 0.f, 0.f, 0.f};
#pragma unroll
        for (int kb = 0; kb < 4; ++kb) {
            int sb = (crow * 256 + kb * 64 + lg * 16) ^ ((crow & 7) << 4);
            bf16x8 chh = *reinterpret_cast<const bf16x8*>(bb + sb);
            bf16x8 cll = *reinterpret_cast<const bf16x8*>(bb + 8192 + sb);
            acc = __builtin_amdgcn_mfma_f32_16x16x32_bf16(chh, zh[kb], acc, 0, 0, 0);
            acc = __builtin_amdgcn_mfma_f32_16x16x32_bf16(chh, zl[kb], acc, 0, 0, 0);
            acc = __builtin_amdgcn_mfma_f32_16x16x32_bf16(cll, zh[kb], acc, 0, 0, 0);
        }

        const int cbase = c * BN + colhalf * 16 + lg * 4;
        float4 cn4 = *reinterpret_cast<const float4*>(&cn_s[cbase]);
        float d0 = fmaf(-2.f, acc[0], xn + cn4.x);
        float d1 = fmaf(-2.f, acc[1], xn + cn4.y);
        float d2 = fmaf(-2.f, acc[2], xn + cn4.z);
        float d3 = fmaf(-2.f, acc[3], xn + cn4.w);
        if (d0 < v1) { v2 = v1; i2 = i1; v1 = d0; i1 = cbase; }
        else if (d0 < v2) { v2 = d0; i2 = cbase; }
        if (d1 < v1) { v2 = v1; i2 = i1; v1 = d1; i1 = cbase + 1; }
        else if (d1 < v2) { v2 = d1; i2 = cbase + 1; }
        if (d2 < v1) { v2 = v1; i2 = i1; v1 = d2; i1 = cbase + 2; }
        else if (d2 < v2) { v2 = d2; i2 = cbase + 2; }
        if (d3 < v1) { v2 = v1; i2 = i1; v1 = d3; i1 = cbase + 3; }
        else if (d3 < v2) { v2 = d3; i2 = cbase + 3; }
        *reinterpret_cast<float4*>(orow + (size_t)c * BN) = make_float4(d0, d1, d2, d3);

        __syncthreads();
        cur ^= 1;
    }

    float* rv1 = reinterpret_cast<float*>(Bsh);
    float* rv2 = rv1 + 256;
    int* ri1 = reinterpret_cast<int*>(rv2 + 256);
    int* ri2 = ri1 + 256;
    {
        const int slot = colhalf * 4 + lg;
        const int rr = rowgrp * 16 + lr;
        rv1[slot * 32 + rr] = v1;
        rv2[slot * 32 + rr] = v2;
        ri1[slot * 32 + rr] = i1;
        ri2[slot * 32 + rr] = i2;
    }
    __syncthreads();

    if (t < BM) {
        float bv = INFINITY, sv = INFINITY;
        int bi = K, si = K;
        for (int s = 0; s < 8; ++s) {
            t2merge(bv, bi, sv, si, rv1[s * 32 + t], ri1[s * 32 + t], rv2[s * 32 + t], ri2[s * 32 + t]);
        }
        bi_s[t] = bi;
        si_s[t] = si;
    }
    __syncthreads();

    float lossv = 0.f;
    if (t < 128) {
        const int rr = t >> 2, t4 = t & 3;
        const int bi = bi_s[rr], si = si_s[rr];
        const float4* zr = reinterpret_cast<const float4*>(z + (size_t)(row_base + rr) * D);
        const float4* c1 = reinterpret_cast<const float4*>(codebook + (size_t)bi * D);
        const float4* c2 = reinterpret_cast<const float4*>(codebook + (size_t)si * D);
        double dd1 = 0.0, dd2 = 0.0;
#pragma unroll
        for (int j = 0; j < 8; ++j) {
            float4 xv = zr[t4 * 8 + j];
            float4 a = c1[t4 * 8 + j];
            float4 b = c2[t4 * 8 + j];
            double e;
            e = (double)xv.x - (double)a.x; dd1 += e * e;
            e = (double)xv.y - (double)a.y; dd1 += e * e;
            e = (double)xv.z - (double)a.z; dd1 += e * e;
            e = (double)xv.w - (double)a.w; dd1 += e * e;
            e = (double)xv.x - (double)b.x; dd2 += e * e;
            e = (double)xv.y - (double)b.y; dd2 += e * e;
            e = (double)xv.z - (double)b.z; dd2 += e * e;
            e = (double)xv.w - (double)b.w; dd2 += e * e;
        }
        dd1 += __shfl_xor(dd1, 1); dd1 += __shfl_xor(dd1, 2);
        dd2 += __shfl_xor(dd2, 1); dd2 += __shfl_xor(dd2, 2);
        if (t4 == 0) {
            int fi = bi; double dmin = dd1;
            if (dd2 < dd1 || (dd2 == dd1 && si < bi)) { fi = si; dmin = dd2; }
            best_s[rr] = fi;
            out_idx[row_base + rr] = (float)fi;
            atomicAdd(&hist[fi], 1);
            lossv = (float)dmin;
        }
    }
#pragma unroll
    for (int o = 32; o > 0; o >>= 1) lossv += __shfl_down(lossv, o);
    if (lane == 0) atomicAdd(loss_accum, lossv);
    __syncthreads();

    {
        const float4* cb4 = reinterpret_cast<const float4*>(codebook);
        float4* zq4 = reinterpret_cast<float4*>(out_zq + (size_t)row_base * D);
#pragma unroll
        for (int k = 0; k < 4; ++k) {
            int f = t + k * 256;
            int r = f >> 5, d4 = f & 31;
            zq4[f] = cb4[(size_t)best_s[r] * 32 + d4];
        }
    }
}

__global__ void vq_finalize(const int* __restrict__ hist, const float* __restrict__ loss_accum,
                            float* __restrict__ out_scalars, int M) {
    __shared__ float red[256];
    int t = threadIdx.x;
    float s = 0.f;
    float invM = 1.0f / (float)M;
#pragma unroll
    for (int k = 0; k < K / 256; ++k) {
        float p = (float)hist[t + k * 256] * invM;
        s += p * logf(p + 1e-10f);
    }
    red[t] = s;
    __syncthreads();
    for (int off = 128; off > 0; off >>= 1) {
        if (t < off) red[t] += red[t + off];
        __syncthreads();
    }
    if (t == 0) {
        float loss = loss_accum[0] / ((float)M * (float)D);
        out_scalars[0] = 0.25f * loss;
        out_scalars[1] = loss;
        out_scalars[2] = expf(-red[0]);
    }
}

extern "C" void kernel_launch(void* const* d_in, const int* in_sizes, int n_in,
                              void* d_out, int out_size, void* d_ws, size_t ws_size,
                              hipStream_t stream) {
    const float* z = (const float*)d_in[0];
    const float* codebook = (const float*)d_in[1];
    int M = in_sizes[0] / D;   // 32768

    float* out = (float*)d_out;
    float* out_zq = out;
    float* out_idx = out + (size_t)M * D;
    float* out_scalars = out_idx + M;
    float* out_dist = out_scalars + 3;

    int* hist = (int*)d_ws;
    float* loss_accum = (float*)((char*)d_ws + 4096);
    float* cnorm = (float*)((char*)d_ws + 8192);
    u16* frag = (u16*)((char*)d_ws + 16384);
    float4* part = (float4*)((char*)d_ws + 540672);

    hipMemsetAsync(d_ws, 0, 8192, stream);
    if (ws_size >= (size_t)540672 + (size_t)16 * M * 16) {
        prep2<<<(K * D / 4) / 256, 256, 0, stream>>>(codebook, frag, cnorm);
        vq_dist<<<(M / 128) * 2, 512, 0, stream>>>(z, frag, cnorm, part, out_dist);
        vq_merge<<<M / 64, 256, 0, stream>>>(z, codebook, part, hist, loss_accum,
                                             out_zq, out_idx);
    } else {
        prep_cb<<<(K * D / 4) / 256, 256, 0, stream>>>(codebook, frag, cnorm);
        vq_main<<<M / BM, 256, 0, stream>>>(z, codebook, cnorm, frag, hist, loss_accum,
                                            out_zq, out_idx, out_dist);
    }
    vq_finalize<<<1, 256, 0, stream>>>(hist, loss_accum, out_scalars, M);
}